// Round 5
// baseline (741.292 us; speedup 1.0000x reference)
//
#include <hip/hip_runtime.h>
#include <hip/hip_bf16.h>

typedef unsigned short u16;
typedef unsigned int   u32;
typedef unsigned long long u64;

using short8 = __attribute__((ext_vector_type(8))) short;
using f32x4  = __attribute__((ext_vector_type(4))) float;
using u16x8  = __attribute__((ext_vector_type(8))) unsigned short;

#define AS_GLOBAL __attribute__((address_space(1)))
#define AS_LDS    __attribute__((address_space(3)))

// ---- bf16 helpers (manual RNE) ----
__device__ __forceinline__ u16 f2b(float x){
  u32 u = __float_as_uint(x);
  u32 r = (u + 0x7FFFu + ((u >> 16) & 1u)) >> 16;
  return (u16)r;
}
__device__ __forceinline__ float b2f(u16 h){ return __uint_as_float(((u32)h) << 16); }

__device__ __forceinline__ void gload16(u16* l, const u16* g){
  __builtin_amdgcn_global_load_lds((const AS_GLOBAL u32*)g, (AS_LDS u32*)l, 16, 0, 0);
}

__device__ __forceinline__ u64 umin64(u64 a, u64 b){ return a < b ? a : b; }

__device__ __forceinline__ u64 shfl_xor_u64(u64 v, int m){
  u32 lo = __shfl_xor((u32)v, m, 64);
  u32 hi = __shfl_xor((u32)(v >> 32), m, 64);
  return ((u64)hi << 32) | lo;
}

// ---- prep kernels ----
__global__ void k_cvt(const float* __restrict__ w, u16* __restrict__ d, int n){
  int i = blockIdx.x * 256 + threadIdx.x;
  if (i < n) d[i] = f2b(w[i]);
}

__global__ void k_cnorm(const float* __restrict__ emb, float* __restrict__ cnorm){
  int v = blockIdx.x, lane = threadIdx.x;
  const float* r = emb + (size_t)v * 512;
  float s = 0.f;
  #pragma unroll
  for (int i = 0; i < 8; ++i){ float x = r[lane + i * 64]; s += x * x; }
  #pragma unroll
  for (int off = 32; off; off >>= 1) s += __shfl_down(s, off, 64);
  if (lane == 0) cnorm[v] = s;
}

// ---- transpose+convert: src f32 [256 b][512 r][256 c] -> d bf16 [b][c][r] ----
__global__ void k_tcvt(const float* __restrict__ src, u16* __restrict__ d){
  __shared__ float t[64][65];
  const int bid = blockIdx.x;
  const int b  = bid >> 5;
  const int rb = (bid >> 2) & 7;
  const int cb = bid & 3;
  const float* s = src + ((size_t)b * 512 + (size_t)rb * 64) * 256 + cb * 64;
  const int tid = threadIdx.x;
  #pragma unroll
  for (int j = 0; j < 4; ++j){
    int fl = j * 256 + tid;
    int r = fl >> 4, c4 = (fl & 15) * 4;
    float4 v = *(const float4*)(s + (size_t)r * 256 + c4);
    t[r][c4 + 0] = v.x; t[r][c4 + 1] = v.y; t[r][c4 + 2] = v.z; t[r][c4 + 3] = v.w;
  }
  __syncthreads();
  u16* o = d + ((size_t)b * 256 + (size_t)cb * 64) * 512 + rb * 64;
  #pragma unroll
  for (int j = 0; j < 2; ++j){
    int fl = j * 256 + tid;
    int c = fl >> 3, r8 = (fl & 7) * 8;
    u16x8 hv;
    #pragma unroll
    for (int i = 0; i < 8; ++i) hv[i] = f2b(t[r8 + i][c]);
    *(u16x8*)(o + (size_t)c * 512 + r8) = hv;
  }
}

// ---- z_q gather ----
__global__ void k_zq(const u64* __restrict__ keys, const float* __restrict__ emb, float* __restrict__ zq){
  int sidx = blockIdx.x * 64 + threadIdx.x;
  int b = sidx >> 8, s = sidx & 255;
  int v = (int)(u32)keys[sidx];
  const float4* er = (const float4*)(emb + (size_t)v * 512);
  float* o = zq + (size_t)b * 512 * 256 + s;
  #pragma unroll 4
  for (int e4 = 0; e4 < 128; ++e4){
    float4 vv = er[e4];
    o[(size_t)(e4 * 4 + 0) * 256] = vv.x;
    o[(size_t)(e4 * 4 + 1) * 256] = vv.y;
    o[(size_t)(e4 * 4 + 2) * 256] = vv.z;
    o[(size_t)(e4 * 4 + 3) * 256] = vv.w;
  }
}

// ---- small GEMM (proven 128x128 2-phase): GEMM1 & GEMM3 ----
template<int MODE>
__global__ __launch_bounds__(256, 4) void k_gemm(
    const u16* __restrict__ Ah,
    const u16* __restrict__ Bh,
    const u64* __restrict__ gkeys,
    const float* __restrict__ bias,
    float* __restrict__ Cout,
    int M, int mtbits)
{
  constexpr int K = 512;
  __shared__ __align__(16) u16 sA[128 * 64];
  __shared__ __align__(16) u16 sB[128 * 64];

  const int tid  = threadIdx.x;
  const int lane = tid & 63;
  const int wid  = tid >> 6;
  const int wm = wid >> 1, wn = wid & 1;

  const int nwg = gridDim.x;
  const int chunk = nwg >> 3;
  const int pb = blockIdx.x;
  const int bid = (pb & 7) * chunk + (pb >> 3);

  const int mt = bid & ((1 << mtbits) - 1);
  const int nt = (bid >> mtbits) & 1;
  const int b  = bid >> (mtbits + 1);
  const int m0 = mt * 128;
  const int n0 = nt * 128;
  const int bbase = b * 256;

  const u16* ga[4];
  const u16* gb[4];
  int ldso[4];
  #pragma unroll
  for (int i = 0; i < 4; ++i){
    int e = i * 256 + tid;
    int r = e >> 3;
    int sl = (e & 7) ^ (r & 7);
    ldso[i] = e * 8;
    ga[i] = Ah + (size_t)(m0 + r) * K + sl * 8;
    size_t brow;
    if (MODE == 2) brow = (size_t)(u32)gkeys[bbase + n0 + r];
    else           brow = (size_t)(bbase + n0 + r);
    gb[i] = Bh + brow * K + sl * 8;
  }

  const f32x4 zero4 = {0.f, 0.f, 0.f, 0.f};
  f32x4 acc[4][4];
  #pragma unroll
  for (int i = 0; i < 4; ++i)
    #pragma unroll
    for (int j = 0; j < 4; ++j) acc[i][j] = zero4;

  int aoff[2][4], boff[2][4];
  #pragma unroll
  for (int ks = 0; ks < 2; ++ks)
    #pragma unroll
    for (int f = 0; f < 4; ++f){
      int rA = wm * 64 + f * 16 + (lane & 15);
      aoff[ks][f] = rA * 64 + (((ks * 4 + (lane >> 4)) ^ (rA & 7)) * 8);
      int rB = wn * 64 + f * 16 + (lane & 15);
      boff[ks][f] = rB * 64 + (((ks * 4 + (lane >> 4)) ^ (rB & 7)) * 8);
    }

  for (int kt = 0; kt < 8; ++kt){
    const int k0 = kt * 64;
    #pragma unroll
    for (int i = 0; i < 4; ++i){
      gload16(&sA[ldso[i]], ga[i] + k0);
      gload16(&sB[ldso[i]], gb[i] + k0);
    }
    __syncthreads();
    #pragma unroll
    for (int ks = 0; ks < 2; ++ks){
      short8 ah[4], bh[4];
      #pragma unroll
      for (int f = 0; f < 4; ++f){
        ah[f] = *(const short8*)&sA[aoff[ks][f]];
        bh[f] = *(const short8*)&sB[boff[ks][f]];
      }
      #pragma unroll
      for (int fm = 0; fm < 4; ++fm)
        #pragma unroll
        for (int fn = 0; fn < 4; ++fn)
          acc[fm][fn] = __builtin_amdgcn_mfma_f32_16x16x32_bf16(ah[fm], bh[fn], acc[fm][fn], 0, 0, 0);
    }
    __syncthreads();
  }

  const int row0 = m0 + wm * 64;
  const int col  = n0 + wn * 64 + (lane & 15);
  float* Cb = Cout + (size_t)b * M * 256;
  #pragma unroll
  for (int fm = 0; fm < 4; ++fm){
    #pragma unroll
    for (int j = 0; j < 4; ++j){
      int row = row0 + fm * 16 + (lane >> 4) * 4 + j;
      float bi = bias[row];
      #pragma unroll
      for (int fn = 0; fn < 4; ++fn)
        Cb[(size_t)row * 256 + col + fn * 16] = acc[fm][fn][j] + bi;
    }
  }
}

// ---- GEMM2: persistent per-batch block, B panel in REGISTERS ----
// One block per b. B = zb[bbase..+255][512]: each wave holds its 64-col slice
// as bf[8 kt][2 ks][4 fn] short8 = 256 VGPR, loaded ONCE from global.
// LDS only quad-buffers A (4 x 32KB, slot^row&7 swizzle, proven 0-conflict).
// Per K-tile: issue 4 gloads A(t+2) -> vmcnt(8) (drains A(t); never 0 until
// tail) -> barrier -> 16 ds_read_b128 (A frags) + 64 MFMA (B from regs).
// LDS/K-tile/CU: 128KB reads + 32KB writes (~1430cy) vs MFMA 2060cy -> MFMA-bound.
// Buffer safety: write buf (t+2)&3; all waves within one barrier region are in
// tile t, reading buf t&3; tiles t,t+1 read (t)&3,(t+1)&3 != (t+2)&3.
// Accumulation order per acc element identical to prior rounds (k ascending).
__global__ __launch_bounds__(512, 1) void k_gemm2(
    const u16* __restrict__ Ah,      // emb_b [4096][512]
    const u16* __restrict__ Bh,      // zb [65536][512]
    const float* __restrict__ cnorm,
    u64* __restrict__ okeys)
{
  __shared__ __align__(16) u16 lds[75776];  // [4x16384 A-bufs][8192 cn][2048 kbuf]

  const int tid  = threadIdx.x;
  const int lane = tid & 63;
  const int wid  = tid >> 6;
  const int wm   = wid >> 2;
  const int wn   = wid & 3;
  const int b    = blockIdx.x;
  const int bbase = b * 256;

  // cnorm -> LDS (read only in epilogues, many barriers later)
  float* cn = (float*)&lds[65536];
  {
    const float4* c4 = (const float4*)cnorm;
    ((float4*)cn)[tid] = c4[tid];
    ((float4*)cn)[tid + 512] = c4[tid + 512];
  }
  __syncthreads();

  // ---- B panel -> registers (issued first; drained by first vmcnt(8)) ----
  short8 bf[8][2][4];
  {
    const u16* bp = Bh + (size_t)(bbase + wn * 64 + (lane & 15)) * 512 + (lane >> 4) * 8;
    #pragma unroll
    for (int kt = 0; kt < 8; ++kt)
      #pragma unroll
      for (int ks = 0; ks < 2; ++ks)
        #pragma unroll
        for (int f = 0; f < 4; ++f)
          bf[kt][ks][f] = *(const short8*)(bp + f * 8192 + kt * 64 + ks * 32);
  }

  // ---- A staging descriptors (4 x 16B per thread per tile) ----
  const u16* ga[4];
  #pragma unroll
  for (int i = 0; i < 4; ++i){
    int e = i * 512 + tid;
    int r = e >> 3;                 // tile row 0..255
    int sl = (e & 7) ^ (r & 7);     // pre-unswizzled source slot
    ga[i] = Ah + (size_t)r * 512 + sl * 8;
  }
  const int dofs = tid * 8;         // + i*4096 + buf*16384

#define STG_A(bufc, off) { _Pragma("unroll") for (int i_ = 0; i_ < 4; ++i_) \
    gload16(&lds[(bufc) * 16384 + i_ * 4096 + dofs], ga[i_] + (off)); }
#define VM8 asm volatile("s_waitcnt vmcnt(8)" ::: "memory");
#define VM4 asm volatile("s_waitcnt vmcnt(4)" ::: "memory");
#define VM0 asm volatile("s_waitcnt vmcnt(0)" ::: "memory");

  // A-frag ds_read bases ((rA&7)==(lane&7) since wm*128,f*16 are mult of 8)
  int aoffK[2];
  #pragma unroll
  for (int ks = 0; ks < 2; ++ks)
    aoffK[ks] = (wm * 128 + (lane & 15)) * 64 + (((ks * 4 + (lane >> 4)) ^ (lane & 7)) * 8);

  const f32x4 zero4 = {0.f, 0.f, 0.f, 0.f};
  f32x4 acc[8][4];
  #pragma unroll
  for (int i = 0; i < 8; ++i)
    #pragma unroll
    for (int j = 0; j < 4; ++j) acc[i][j] = zero4;

  u64 best[4];
  #pragma unroll
  for (int i = 0; i < 4; ++i) best[i] = ~0ull;

  // prologue: stage tiles 0,1
  STG_A(0, 0)
  STG_A(1, 64)

  for (int mt = 0; mt < 16; ++mt){
    const size_t amt = (size_t)mt * 131072;

    #pragma unroll
    for (int kt = 0; kt < 8; ++kt){
      // stage A(tau+2)
      if (kt < 6){
        STG_A((kt + 2) & 3, amt + (kt + 2) * 64)
      } else {
        if (mt < 15) STG_A((kt + 2) & 3, amt + 131072 + (kt - 6) * 64)
      }
      // counted wait: drains exactly A(tau); tail drains remaining
      if (kt < 6){ VM8 }
      else if (kt == 6){ if (mt < 15){ VM8 } else { VM4 } }
      else          { if (mt < 15){ VM8 } else { VM0 } }
      __builtin_amdgcn_s_barrier();
      __builtin_amdgcn_sched_barrier(0);

      const int rbuf = (kt & 3) * 16384;
      #pragma unroll
      for (int ks = 0; ks < 2; ++ks){
        short8 ah[8];
        #pragma unroll
        for (int f = 0; f < 8; ++f)
          ah[f] = *(const short8*)&lds[rbuf + aoffK[ks] + f * 1024];
        __builtin_amdgcn_s_setprio(1);
        #pragma unroll
        for (int fm = 0; fm < 8; ++fm)
          #pragma unroll
          for (int f = 0; f < 4; ++f)
            acc[fm][f] = __builtin_amdgcn_mfma_f32_16x16x32_bf16(ah[fm], bf[kt][ks][f], acc[fm][f], 0, 0, 0);
        __builtin_amdgcn_s_setprio(0);
      }
    }

    // per-mt epilogue: fold scores into running best (regs + broadcast LDS cn)
    #pragma unroll
    for (int fn = 0; fn < 4; ++fn){
      #pragma unroll
      for (int fm = 0; fm < 8; ++fm){
        #pragma unroll
        for (int j = 0; j < 4; ++j){
          int v = mt * 256 + wm * 128 + fm * 16 + (lane >> 4) * 4 + j;
          float sc = cn[v] - 2.0f * acc[fm][fn][j];
          u32 o = __float_as_uint(sc);
          o = (o & 0x80000000u) ? ~o : (o | 0x80000000u);
          best[fn] = umin64(best[fn], ((u64)o << 32) | (u32)v);
        }
      }
    }
    #pragma unroll
    for (int i = 0; i < 8; ++i)
      #pragma unroll
      for (int j = 0; j < 4; ++j) acc[i][j] = zero4;
  }

  // block-level reduce + single store (no atomics)
  #pragma unroll
  for (int fn = 0; fn < 4; ++fn){
    best[fn] = umin64(best[fn], shfl_xor_u64(best[fn], 16));
    best[fn] = umin64(best[fn], shfl_xor_u64(best[fn], 32));
  }
  u64* kbuf = (u64*)&lds[73728];
  __syncthreads();
  if (lane < 16){
    #pragma unroll
    for (int fn = 0; fn < 4; ++fn)
      kbuf[wm * 256 + wn * 64 + fn * 16 + lane] = best[fn];
  }
  __syncthreads();
  if (tid < 256)
    okeys[bbase + tid] = umin64(kbuf[tid], kbuf[256 + tid]);

#undef STG_A
#undef VM8
#undef VM4
#undef VM0
}

extern "C" void kernel_launch(void* const* d_in, const int* in_sizes, int n_in,
                              void* d_out, int out_size, void* d_ws, size_t ws_size,
                              hipStream_t stream){
  const float* x      = (const float*)d_in[0];
  const float* pre_w  = (const float*)d_in[1];
  const float* pre_b  = (const float*)d_in[2];
  const float* emb    = (const float*)d_in[3];
  const float* post_w = (const float*)d_in[4];
  const float* post_b = (const float*)d_in[5];

  float* z_out   = (float*)d_out;              // [256][512][256]
  float* zq_out  = z_out + 33554432;           // [256][512][256]
  float* rec_out = z_out + 67108864;           // [256][512][256]

  char* w = (char*)d_ws;
  u16* prew_b  = (u16*)(w);                    // 512KB
  u16* postw_b = (u16*)(w + 524288);           // 512KB
  u16* emb_b   = (u16*)(w + 1048576);          // 4MB
  float* cnorm = (float*)(w + 5242880);        // 16KB
  u64* keys    = (u64*)(w + 5259264);          // 512KB
  u16* xb      = (u16*)(w + 5783552);          // 64MB [65536][512] bf16
  u16* zb = xb;                                // z^T bf16 aliases xb (disjoint lifetime)

  k_cvt  <<<1024, 256, 0, stream>>>(pre_w, prew_b, 262144);
  k_cvt  <<<1024, 256, 0, stream>>>(post_w, postw_b, 262144);
  k_cvt  <<<8192, 256, 0, stream>>>(emb, emb_b, 2097152);
  k_cnorm<<<4096, 64, 0, stream>>>(emb, cnorm);

  // x [b][c][s] -> xb [b][s][c]
  k_tcvt<<<8192, 256, 0, stream>>>(x, xb);

  // GEMM1: z = pre_w * x + pre_b
  k_gemm<0><<<256 * 2 * 4, 256, 0, stream>>>(prew_b, xb,
      nullptr, pre_b, z_out, 512, 2);

  // z [b][e][s] -> zb [b][s][e]
  k_tcvt<<<8192, 256, 0, stream>>>(z_out, zb);

  // GEMM2: persistent per-batch scores + argmin -> keys (B in registers)
  k_gemm2<<<256, 512, 0, stream>>>(emb_b, zb, cnorm, keys);

  // z_q gather (exact f32)
  k_zq<<<1024, 64, 0, stream>>>(keys, emb, zq_out);

  // GEMM3: rec = post_w * z_q + post_b  (B staged by gathering emb_b rows via tokens)
  k_gemm<2><<<256 * 2 * 4, 256, 0, stream>>>(postw_b, emb_b,
      keys, post_b, rec_out, 512, 2);
}